// Round 10
// baseline (725.793 us; speedup 1.0000x reference)
//
#include <hip/hip_runtime.h>
#include <hip/hip_cooperative_groups.h>
#include <math.h>

namespace cg = cooperative_groups;

#define N_CELLS 2048
#define D_IN 512
#define D_HID 1024
#define D_OUT 512

typedef __attribute__((ext_vector_type(8))) short bf16x8;
typedef __attribute__((ext_vector_type(4))) float f32x4;
typedef __attribute__((ext_vector_type(4))) short short4v;

#define MFMA16(a, b, c) __builtin_amdgcn_mfma_f32_16x16x32_bf16(a, b, c, 0, 0, 0)

__device__ __forceinline__ short f2bf(float f) {
  union { float f; unsigned u; } v; v.f = f;
  unsigned r = (v.u + 0x7FFFu + ((v.u >> 16) & 1u)) >> 16;
  return (short)r;
}

__device__ __forceinline__ float bf2f(unsigned short u) {
  union { unsigned u; float f; } v; v.u = ((unsigned)u) << 16; return v.f;
}

__device__ __forceinline__ bf16x8 neg8(bf16x8 v) {
  union { bf16x8 s; unsigned u[4]; } a; a.s = v;
#pragma unroll
  for (int i = 0; i < 4; ++i) a.u[i] ^= 0x80008000u;
  return a.s;
}

__device__ __forceinline__ void gl_lds16(const void* g, void* l) {
  __builtin_amdgcn_global_load_lds(
      (const __attribute__((address_space(1))) void*)g,
      (__attribute__((address_space(3))) void*)l, 16, 0, 0);
}

struct P {
  const float *x, *h_re, *h_im;
  const float *ea_wr, *ea_br, *ea_wi, *ea_bi;
  const float *eg_wr, *eg_br, *eg_wi, *eg_bi;
  const float *gz_w, *gz_b, *gr_w, *gr_b;
  const float *ghr_w, *ghr_b, *ghi_w, *ghi_b;
  const float *oh_w, *oh_b;
  const int *step;
  short *wdrT, *wdiT, *gzwT, *grwT, *ghrwT, *ghiwT;
  short *hbre, *hbim, *gatesA, *candAre, *candAim;
  float *ore, *oim;
  unsigned short *zbuf;
  float *bpartr, *bparti, *tens, *fsbuf, *wsoft, *cpart, *ppart;
  float *pred_out, *meanT_out, *nhre, *nhim;
};

// ================= phase device functions =================

// prep: u in [0,8736)
__device__ __forceinline__ void dev_prep(const P& p, int u, int tid, short* lds) {
  if (u < 6144) {
    float* ts0 = (float*)lds;
    const int z = u / 1536, idx = u % 1536;
    const int xx = idx % 48, yy = idx / 48;
    const float* w = (z == 0) ? p.gz_w : (z == 1) ? p.gr_w : (z == 2) ? p.ghr_w : p.ghi_w;
    short* wT = (z == 0) ? p.gzwT : (z == 1) ? p.grwT : (z == 2) ? p.ghrwT : p.ghiwT;
    const int k0 = xx * 32, n0 = yy * 32;
    const int c = tid & 31, r4 = tid >> 5;
    __syncthreads();
#pragma unroll
    for (int i = 0; i < 4; ++i) {
      int kl = r4 * 4 + i;
      int k = k0 + kl;
      int srcrow = (k < 512) ? k : k + 1;
      ts0[kl * 33 + c] = w[(size_t)srcrow * D_HID + n0 + c];
    }
    __syncthreads();
#pragma unroll
    for (int i = 0; i < 4; ++i) {
      int nl = r4 * 4 + i;
      wT[(size_t)(n0 + nl) * 1536 + k0 + c] = f2bf(ts0[c * 33 + nl]);
    }
  } else if (u < 6656) {
    float* ts0 = (float*)lds;
    float* ts1 = ts0 + 32 * 33;
    const int idx = u - 6144;
    const int xx = idx & 31, yy = idx >> 5;
    const int k0 = xx * 32, n0 = yy * 32;
    const int c = tid & 31, r4 = tid >> 5;
    __syncthreads();
#pragma unroll
    for (int i = 0; i < 4; ++i) {
      int kl = r4 * 4 + i;
      int src = (512 + k0 + kl) * D_OUT + n0 + c;
      ts0[kl * 33 + c] = p.ea_wr[src] - p.eg_wr[src];
      ts1[kl * 33 + c] = p.ea_wi[src] - p.eg_wi[src];
    }
    __syncthreads();
#pragma unroll
    for (int i = 0; i < 4; ++i) {
      int nl = r4 * 4 + i;
      int dst = (n0 + nl) * D_HID + k0 + c;
      p.wdrT[dst] = f2bf(ts0[c * 33 + nl]);
      p.wdiT[dst] = f2bf(ts1[c * 33 + nl]);
    }
  } else if (u < 8704) {
    const int idx = u - 6656;
    if (tid == 0) p.tens[idx] = 0.f;
    int idx4 = (idx * 256 + tid) * 4;
    int m = idx4 >> 10, n = idx4 & 1023;
    float4 hr = *(const float4*)&p.h_re[idx4];
    float4 hi = *(const float4*)&p.h_im[idx4];
    short4v br, bi, bm;
    br.x = f2bf(hr.x); br.y = f2bf(hr.y); br.z = f2bf(hr.z); br.w = f2bf(hr.w);
    bi.x = f2bf(hi.x); bi.y = f2bf(hi.y); bi.z = f2bf(hi.z); bi.w = f2bf(hi.w);
    bm.x = f2bf(sqrtf(hr.x * hr.x + hi.x * hi.x));
    bm.y = f2bf(sqrtf(hr.y * hr.y + hi.y * hi.y));
    bm.z = f2bf(sqrtf(hr.z * hr.z + hi.z * hi.z));
    bm.w = f2bf(sqrtf(hr.w * hr.w + hi.w * hi.w));
    *(short4v*)&p.hbre[idx4] = br;
    *(short4v*)&p.hbim[idx4] = bi;
    *(short4v*)&p.gatesA[(size_t)m * 1536 + 512 + n] = bm;
  } else if (u < 8720) {
    const int idx = u - 8704;
    int n = (idx & 1) * 256 + tid;
    int kc = idx >> 1;
    float sr = 0.f, si = 0.f;
    for (int i = 0; i < 64; ++i) {
      int k = kc * 64 + i;
      float xv = p.x[k];
      int j = k * D_OUT + n;
      sr += xv * (p.ea_wr[j] - p.eg_wr[j]);
      si += xv * (p.ea_wi[j] - p.eg_wi[j]);
    }
    p.bpartr[kc * D_OUT + n] = sr;
    p.bparti[kc * D_OUT + n] = si;
  } else {
    const int idx = u - 8720;
    int i = idx * 1024 + tid * 4;
    *(float4*)&p.fsbuf[i] = (float4){0.f, 0.f, 0.f, 0.f};
  }
}

// engine: unit in [0,512); tile 64x32, BK=64
__device__ __forceinline__ void dev_engine(const P& p, int unit, int tid, short* lds) {
  short* Ar = lds;
  short* Ai = lds + 4096;
  short* Brs = lds + 8192;
  short* Bis = lds + 10240;
  const int wid = tid >> 6, lane = tid & 63;
  const int quad = lane >> 4, lcol = lane & 15;
  const int m0 = (unit & 31) * 64, n0 = (unit >> 5) * 32;
  const int wm = wid * 16;
  f32x4 accre[2], accim[2];
#pragma unroll
  for (int nt = 0; nt < 2; ++nt) {
    accre[nt] = (f32x4){0.f, 0.f, 0.f, 0.f};
    accim[nt] = (f32x4){0.f, 0.f, 0.f, 0.f};
  }
  for (int k0 = 0; k0 < D_HID; k0 += 64) {
    __syncthreads();
#pragma unroll
    for (int i = 0; i < 2; ++i) {
      int c = i * 256 + tid;
      int kh = c >> 8, row = (c >> 2) & 63, kq = c & 3;
      size_t g = (size_t)(m0 + row) * D_HID + k0 + kh * 32 + kq * 8;
      gl_lds16(p.hbre + g, &Ar[c * 8]);
      gl_lds16(p.hbim + g, &Ai[c * 8]);
    }
    {
      int c = tid;
      int kh = c >> 7, row = (c >> 2) & 31, kq = c & 3;
      size_t g = (size_t)(n0 + row) * D_HID + k0 + kh * 32 + kq * 8;
      gl_lds16(p.wdrT + g, &Brs[c * 8]);
      gl_lds16(p.wdiT + g, &Bis[c * 8]);
    }
    __syncthreads();
#pragma unroll
    for (int kh = 0; kh < 2; ++kh) {
      bf16x8 ar, ai, br[2], bi[2];
      int aoff = kh * 2048 + (wm + lcol) * 32 + quad * 8;
      ar = *(const bf16x8*)&Ar[aoff];
      ai = *(const bf16x8*)&Ai[aoff];
#pragma unroll
      for (int nt = 0; nt < 2; ++nt) {
        int boff = kh * 1024 + (nt * 16 + lcol) * 32 + quad * 8;
        br[nt] = *(const bf16x8*)&Brs[boff];
        bi[nt] = *(const bf16x8*)&Bis[boff];
      }
      bf16x8 ani = neg8(ai);
#pragma unroll
      for (int nt = 0; nt < 2; ++nt) {
        accre[nt] = MFMA16(ar, br[nt], accre[nt]);
        accre[nt] = MFMA16(ani, bi[nt], accre[nt]);
        accim[nt] = MFMA16(ar, bi[nt], accim[nt]);
        accim[nt] = MFMA16(ai, br[nt], accim[nt]);
      }
    }
  }
  float biasre[2], biasim[2];
#pragma unroll
  for (int nt = 0; nt < 2; ++nt) {
    int n = n0 + nt * 16 + lcol;
    float sr = 0.f, si = 0.f;
#pragma unroll
    for (int kc = 0; kc < 8; ++kc) { sr += p.bpartr[kc * D_OUT + n]; si += p.bparti[kc * D_OUT + n]; }
    float brd = p.ea_br[n] - p.eg_br[n];
    float bid = p.ea_bi[n] - p.eg_bi[n];
    biasre[nt] = sr + brd - bid;
    biasim[nt] = si + brd + bid;
  }
#pragma unroll
  for (int r = 0; r < 4; ++r) {
    int m = m0 + wm + quad * 4 + r;
    float t = 0.f;
#pragma unroll
    for (int nt = 0; nt < 2; ++nt) {
      int n = n0 + nt * 16 + lcol;
      float cre = accre[nt][r] + biasre[nt];
      float cim = accim[nt][r] + biasim[nt];
      t += cre * cre + cim * cim;
      p.ore[(size_t)m * D_OUT + n] = cre;
      p.oim[(size_t)m * D_OUT + n] = cim;
      p.gatesA[(size_t)m * 1536 + n] = f2bf(sqrtf(cre * cre + cim * cim));
      p.candAre[(size_t)m * 1536 + n] = f2bf(cre);
      p.candAim[(size_t)m * 1536 + n] = f2bf(cim);
    }
#pragma unroll
    for (int off = 1; off < 16; off <<= 1) t += __shfl_xor(t, off);
    if (lcol == 0) atomicAdd(&p.tens[m], t * (1.f / 512.f));
  }
}

// gates: unit in [0,1024); tile 64x64, BK=64
__device__ __forceinline__ void dev_gates(const P& p, int unit, int tid, short* lds) {
  short* As = lds;
  short* Bs = lds + 4096;
  const int is_z = (unit < 512);
  const int bb = unit & 511;
  const short* Bt = is_z ? p.gzwT : p.grwT;
  const int wid = tid >> 6, lane = tid & 63;
  const int quad = lane >> 4, lcol = lane & 15;
  const int m0 = (bb & 31) * 64, n0 = (bb >> 5) * 64;
  const int wm = (wid >> 1) * 32, wn = (wid & 1) * 32;
  f32x4 acc[2][2];
#pragma unroll
  for (int mt = 0; mt < 2; ++mt)
#pragma unroll
    for (int nt = 0; nt < 2; ++nt) acc[mt][nt] = (f32x4){0.f, 0.f, 0.f, 0.f};
  for (int k0 = 0; k0 < 1536; k0 += 64) {
    __syncthreads();
#pragma unroll
    for (int i = 0; i < 2; ++i) {
      int c = i * 256 + tid;
      int kh = c >> 8, row = (c >> 2) & 63, kq = c & 3;
      gl_lds16(p.gatesA + (size_t)(m0 + row) * 1536 + k0 + kh * 32 + kq * 8, &As[c * 8]);
      gl_lds16(Bt + (size_t)(n0 + row) * 1536 + k0 + kh * 32 + kq * 8, &Bs[c * 8]);
    }
    __syncthreads();
#pragma unroll
    for (int kh = 0; kh < 2; ++kh) {
      bf16x8 a[2], b[2];
#pragma unroll
      for (int mt = 0; mt < 2; ++mt)
        a[mt] = *(const bf16x8*)&As[kh * 2048 + (wm + mt * 16 + lcol) * 32 + quad * 8];
#pragma unroll
      for (int nt = 0; nt < 2; ++nt)
        b[nt] = *(const bf16x8*)&Bs[kh * 2048 + (wn + nt * 16 + lcol) * 32 + quad * 8];
#pragma unroll
      for (int mt = 0; mt < 2; ++mt)
#pragma unroll
        for (int nt = 0; nt < 2; ++nt)
          acc[mt][nt] = MFMA16(a[mt], b[nt], acc[mt][nt]);
    }
  }
#pragma unroll
  for (int mt = 0; mt < 2; ++mt)
#pragma unroll
    for (int nt = 0; nt < 2; ++nt)
#pragma unroll
      for (int r = 0; r < 4; ++r) {
        int m = m0 + wm + mt * 16 + quad * 4 + r;
        int n = n0 + wn + nt * 16 + lcol;
        float tv = p.tens[m];
        if (is_z) {
          float zp = acc[mt][nt][r] + p.gz_b[n] + tv * p.gz_w[(size_t)512 * D_HID + n];
          p.zbuf[(size_t)m * D_HID + n] = (unsigned short)f2bf(1.f / (1.f + expf(-zp)));
        } else {
          float rp = acc[mt][nt][r] + p.gr_b[n] + tv * p.gr_w[(size_t)512 * D_HID + n];
          float rr = 1.f / (1.f + expf(-rp));
          p.candAre[(size_t)m * 1536 + 512 + n] = f2bf(rr * p.h_re[(size_t)m * D_HID + n]);
          p.candAim[(size_t)m * 1536 + 512 + n] = f2bf(rr * p.h_im[(size_t)m * D_HID + n]);
        }
      }
}

// cand: unit in [0,1024); tile 64x64, BK=64
__device__ __forceinline__ void dev_cand(const P& p, int unit, int tid, short* lds) {
  short* As = lds;
  short* Bs = lds + 4096;
  const int is_re = (unit < 512);
  const int bb = unit & 511;
  const short* A = is_re ? p.candAre : p.candAim;
  const short* Bt = is_re ? p.ghrwT : p.ghiwT;
  const float* bias = is_re ? p.ghr_b : p.ghi_b;
  const float* h = is_re ? p.h_re : p.h_im;
  float* outp = is_re ? p.nhre : p.nhim;
  const int wid = tid >> 6, lane = tid & 63;
  const int quad = lane >> 4, lcol = lane & 15;
  const int m0 = (bb & 31) * 64, n0 = (bb >> 5) * 64;
  const int wm = (wid >> 1) * 32, wn = (wid & 1) * 32;
  f32x4 acc[2][2];
#pragma unroll
  for (int mt = 0; mt < 2; ++mt)
#pragma unroll
    for (int nt = 0; nt < 2; ++nt) acc[mt][nt] = (f32x4){0.f, 0.f, 0.f, 0.f};
  for (int k0 = 0; k0 < 1536; k0 += 64) {
    __syncthreads();
#pragma unroll
    for (int i = 0; i < 2; ++i) {
      int c = i * 256 + tid;
      int kh = c >> 8, row = (c >> 2) & 63, kq = c & 3;
      gl_lds16(A + (size_t)(m0 + row) * 1536 + k0 + kh * 32 + kq * 8, &As[c * 8]);
      gl_lds16(Bt + (size_t)(n0 + row) * 1536 + k0 + kh * 32 + kq * 8, &Bs[c * 8]);
    }
    __syncthreads();
#pragma unroll
    for (int kh = 0; kh < 2; ++kh) {
      bf16x8 a[2], b[2];
#pragma unroll
      for (int mt = 0; mt < 2; ++mt)
        a[mt] = *(const bf16x8*)&As[kh * 2048 + (wm + mt * 16 + lcol) * 32 + quad * 8];
#pragma unroll
      for (int nt = 0; nt < 2; ++nt)
        b[nt] = *(const bf16x8*)&Bs[kh * 2048 + (wn + nt * 16 + lcol) * 32 + quad * 8];
#pragma unroll
      for (int mt = 0; mt < 2; ++mt)
#pragma unroll
        for (int nt = 0; nt < 2; ++nt)
          acc[mt][nt] = MFMA16(a[mt], b[nt], acc[mt][nt]);
    }
  }
#pragma unroll
  for (int mt = 0; mt < 2; ++mt)
#pragma unroll
    for (int nt = 0; nt < 2; ++nt)
#pragma unroll
      for (int r = 0; r < 4; ++r) {
        int m = m0 + wm + mt * 16 + quad * 4 + r;
        int n = n0 + wn + nt * 16 + lcol;
        float pre = acc[mt][nt][r] + bias[n];
        if (is_re) pre += p.tens[m] * p.ghr_w[(size_t)512 * D_HID + n];
        float cand = tanhf(pre);
        float z = bf2f(p.zbuf[(size_t)m * D_HID + n]);
        float hv = h[(size_t)m * D_HID + n];
        outp[(size_t)m * D_HID + n] = (1.f - z) * hv + z * cand;
      }
}

// fsum: unit in [0,128)
__device__ __forceinline__ void dev_fsum(const P& p, int unit, int tid) {
  int f = (unit & 63) >> 3, rc = unit & 7, comp = unit >> 6;
  const float* src = comp ? p.nhim : p.nhre;
  float* fs = p.fsbuf + (size_t)comp * 8192;
  int row0 = f * 256 + rc * 32;
#pragma unroll
  for (int nc = 0; nc < 4; ++nc) {
    int n = nc * 256 + tid;
    float s = 0.f;
    const float* base = src + (size_t)row0 * D_HID + n;
    for (int j = 0; j < 32; ++j) s += base[(size_t)j * D_HID];
    atomicAdd(&fs[(size_t)n * 8 + f], s);
  }
}

// stats: single unit (256 threads)
__device__ __forceinline__ void dev_stats(const P& p, int tid, short* lds) {
  float* red = (float*)lds;
  const int wid = tid >> 6, lane = tid & 63;
  float v[8];
  float mx = -1e30f;
#pragma unroll
  for (int k2 = 0; k2 < 8; ++k2) { v[k2] = p.tens[tid + 256 * k2]; mx = fmaxf(mx, v[k2]); }
  for (int off = 1; off < 64; off <<= 1) mx = fmaxf(mx, __shfl_xor(mx, off));
  if (lane == 0) red[wid] = mx;
  __syncthreads();
  float gmax = fmaxf(fmaxf(red[0], red[1]), fmaxf(red[2], red[3]));
  __syncthreads();
  float e[8], ps = 0.f, pt = 0.f;
#pragma unroll
  for (int k2 = 0; k2 < 8; ++k2) { e[k2] = expf(v[k2] - gmax); ps += e[k2]; pt += v[k2]; }
  for (int off = 1; off < 64; off <<= 1) ps += __shfl_xor(ps, off);
  if (lane == 0) red[wid] = ps;
  __syncthreads();
  float gsum = red[0] + red[1] + red[2] + red[3];
  __syncthreads();
  for (int off = 1; off < 64; off <<= 1) pt += __shfl_xor(pt, off);
  if (lane == 0) red[wid] = pt;
  __syncthreads();
  if (tid == 0) p.meanT_out[0] = (red[0] + red[1] + red[2] + red[3]) * (1.f / 2048.f);
  float inv = 1.f / gsum;
#pragma unroll
  for (int k2 = 0; k2 < 8; ++k2) p.wsoft[tid + 256 * k2] = e[k2] * inv;
}

// sync-apply + comb partials: unit in [0,8256)
__device__ __forceinline__ void dev_syncomb(const P& p, int u, int tid) {
  if (u < 8192) {
    int idx = u * 256 + tid;
    int m = idx >> 10, n = idx & 1023;
    int f = m >> 8;
    const float* f0 = p.fsbuf + (size_t)n * 8;
    const float* f1 = p.fsbuf + 8192 + (size_t)n * 8;
    float gr = 0.f, gi = 0.f;
#pragma unroll
    for (int ff = 0; ff < 8; ++ff) { gr += f0[ff]; gi += f1[ff]; }
    float fr = f0[f], fi = f1[f];
    float vr = p.nhre[idx], vi = p.nhim[idx];
    vr = 0.85f * vr + 0.15f * (fr * (1.f / 256.f));
    vi = 0.85f * vi + 0.15f * (fi * (1.f / 256.f));
    if (p.step[0] > 5 && (m & 255) < 64) {
      vr = 0.85f * vr + 0.15f * (gr * (1.f / 2048.f));
      vi = 0.85f * vi + 0.15f * (gi * (1.f / 2048.f));
    }
    p.nhre[idx] = vr;
    p.nhim[idx] = vi;
  } else {
    int v2 = u - 8192;
    int j = (v2 & 3) * 256 + tid;
    int mc = v2 >> 2;
    const float* src = (j < 512) ? p.ore : p.oim;
    int col = j & 511;
    float s = 0.f;
    for (int i = 0; i < 128; ++i) {
      int m = mc * 128 + i;
      s += p.wsoft[m] * src[(size_t)m * D_OUT + col];
    }
    p.cpart[(size_t)mc * 1024 + j] = s;
  }
}

// pred partials: unit in [0,16)
__device__ __forceinline__ void dev_predpart(const P& p, int unit, int tid, short* lds) {
  float* combs = (float*)lds;
  int jc = unit >> 1;
  if (tid < 128) {
    float s = 0.f;
#pragma unroll
    for (int mc = 0; mc < 16; ++mc) s += p.cpart[(size_t)mc * 1024 + jc * 128 + tid];
    combs[tid] = s;
  }
  __syncthreads();
  int n = (unit & 1) * 256 + tid;
  float s = 0.f;
  for (int i = 0; i < 128; ++i)
    s += combs[i] * p.oh_w[(size_t)(jc * 128 + i) * D_IN + n];
  p.ppart[(size_t)jc * D_IN + n] = s;
}

// pred reduce: unit in [0,2)
__device__ __forceinline__ void dev_predred(const P& p, int unit, int tid) {
  int n = unit * 256 + tid;
  float s = p.oh_b[n];
#pragma unroll
  for (int jc = 0; jc < 8; ++jc) s += p.ppart[(size_t)jc * D_IN + n];
  p.pred_out[n] = s;
}

// ================= cooperative mega kernel (512 blocks) =================
__global__ __launch_bounds__(256, 2) void k_mega(P p) {
  __shared__ __align__(16) short lds[12288];  // 24 KB
  cg::grid_group grid = cg::this_grid();
  const int bx = blockIdx.x;
  const int tid = threadIdx.x;
  for (int u = bx; u < 8736; u += 512) dev_prep(p, u, tid, lds);
  grid.sync();
  dev_engine(p, bx, tid, lds);
  grid.sync();
  for (int u = bx; u < 1024; u += 512) dev_gates(p, u, tid, lds);
  grid.sync();
  for (int u = bx; u < 1024; u += 512) dev_cand(p, u, tid, lds);
  grid.sync();
  if (bx < 128) dev_fsum(p, bx, tid);
  else if (bx == 128) dev_stats(p, tid, lds);
  grid.sync();
  for (int u = bx; u < 8256; u += 512) dev_syncomb(p, u, tid);
  grid.sync();
  if (bx < 16) dev_predpart(p, bx, tid, lds);
  grid.sync();
  if (bx < 2) dev_predred(p, bx, tid);
}

// ================= fallback per-phase kernels =================
__global__ __launch_bounds__(256) void k_prep_k(P p) {
  __shared__ __align__(16) short lds[12288];
  dev_prep(p, blockIdx.x, threadIdx.x, lds);
}
__global__ __launch_bounds__(256) void k_engine_k(P p) {
  __shared__ __align__(16) short lds[12288];
  dev_engine(p, blockIdx.x, threadIdx.x, lds);
}
__global__ __launch_bounds__(256) void k_gates_k(P p) {
  __shared__ __align__(16) short lds[12288];
  dev_gates(p, blockIdx.x, threadIdx.x, lds);
}
__global__ __launch_bounds__(256) void k_cand_k(P p) {
  __shared__ __align__(16) short lds[12288];
  dev_cand(p, blockIdx.x, threadIdx.x, lds);
}
__global__ __launch_bounds__(256) void k_fs_k(P p) {
  __shared__ __align__(16) short lds[64];
  if (blockIdx.x < 128) dev_fsum(p, blockIdx.x, threadIdx.x);
  else dev_stats(p, threadIdx.x, lds);
}
__global__ __launch_bounds__(256) void k_sc_k(P p) {
  dev_syncomb(p, blockIdx.x, threadIdx.x);
}
__global__ __launch_bounds__(256) void k_pp_k(P p) {
  __shared__ __align__(16) short lds[256];
  dev_predpart(p, blockIdx.x, threadIdx.x, lds);
}
__global__ __launch_bounds__(256) void k_pr_k(P p) {
  dev_predred(p, blockIdx.x, threadIdx.x);
}

// ================= launcher =================
extern "C" void kernel_launch(void* const* d_in, const int* in_sizes, int n_in,
                              void* d_out, int out_size, void* d_ws, size_t ws_size,
                              hipStream_t stream) {
  float* out = (float*)d_out;

  char* wp = (char*)d_ws;
  auto carve = [&](size_t bytes) { char* r = wp; wp += (bytes + 255) & ~(size_t)255; return r; };
  short* wdrT   = (short*)carve(512 * 1024 * 2);
  short* wdiT   = (short*)carve(512 * 1024 * 2);
  short* gzwT   = (short*)carve(1024 * 1536 * 2);
  short* grwT   = (short*)carve(1024 * 1536 * 2);
  short* ghrwT  = (short*)carve(1024 * 1536 * 2);
  short* ghiwT  = (short*)carve(1024 * 1536 * 2);
  short* hbre   = (short*)carve(2048 * 1024 * 2);
  short* hbim   = (short*)carve(2048 * 1024 * 2);
  short* gatesA = (short*)carve((size_t)2048 * 1536 * 2);
  short* candAre= (short*)carve((size_t)2048 * 1536 * 2);
  short* candAim= (short*)carve((size_t)2048 * 1536 * 2);
  float* ore    = (float*)carve(2048 * 512 * 4);
  float* oim    = (float*)carve(2048 * 512 * 4);
  unsigned short* zbuf = (unsigned short*)carve((size_t)2048 * 1024 * 2);
  float* bpartr = (float*)carve(8 * 512 * 4);
  float* bparti = (float*)carve(8 * 512 * 4);
  float* tens   = (float*)carve(2048 * 4);
  float* fsbuf  = (float*)carve(2 * 8192 * 4);
  float* wsoft  = (float*)carve(2048 * 4);
  float* cpart  = (float*)carve(16 * 1024 * 4);
  float* ppart  = (float*)carve(8 * 512 * 4);

  P prm;
  prm.x     = (const float*)d_in[0];
  prm.h_re  = (const float*)d_in[1];
  prm.h_im  = (const float*)d_in[2];
  prm.ea_wr = (const float*)d_in[3];
  prm.ea_br = (const float*)d_in[4];
  prm.ea_wi = (const float*)d_in[5];
  prm.ea_bi = (const float*)d_in[6];
  prm.eg_wr = (const float*)d_in[7];
  prm.eg_br = (const float*)d_in[8];
  prm.eg_wi = (const float*)d_in[9];
  prm.eg_bi = (const float*)d_in[10];
  prm.gz_w  = (const float*)d_in[11];
  prm.gz_b  = (const float*)d_in[12];
  prm.gr_w  = (const float*)d_in[13];
  prm.gr_b  = (const float*)d_in[14];
  prm.ghr_w = (const float*)d_in[15];
  prm.ghr_b = (const float*)d_in[16];
  prm.ghi_w = (const float*)d_in[17];
  prm.ghi_b = (const float*)d_in[18];
  prm.oh_w  = (const float*)d_in[19];
  prm.oh_b  = (const float*)d_in[20];
  prm.step  = (const int*)d_in[21];
  prm.wdrT = wdrT; prm.wdiT = wdiT;
  prm.gzwT = gzwT; prm.grwT = grwT; prm.ghrwT = ghrwT; prm.ghiwT = ghiwT;
  prm.hbre = hbre; prm.hbim = hbim;
  prm.gatesA = gatesA; prm.candAre = candAre; prm.candAim = candAim;
  prm.ore = ore; prm.oim = oim; prm.zbuf = zbuf;
  prm.bpartr = bpartr; prm.bparti = bparti;
  prm.tens = tens; prm.fsbuf = fsbuf; prm.wsoft = wsoft;
  prm.cpart = cpart; prm.ppart = ppart;
  prm.pred_out = out;
  prm.meanT_out = out + 512;
  prm.nhre = out + 513;
  prm.nhim = out + 513 + N_CELLS * D_HID;

  // capacity pre-check for cooperative launch (host-side queries, capture-safe)
  int dev = 0;
  (void)hipGetDevice(&dev);
  int cus = 0;
  (void)hipDeviceGetAttribute(&cus, hipDeviceAttributeMultiprocessorCount, dev);
  int maxBlocksPerCU = 0;
  hipError_t occErr = hipOccupancyMaxActiveBlocksPerMultiprocessor(&maxBlocksPerCU, k_mega, 256, 0);
  bool coop_ok = (occErr == hipSuccess) && (cus > 0) &&
                 ((long long)maxBlocksPerCU * cus >= 512);

  hipError_t lerr = hipErrorUnknown;
  if (coop_ok) {
    void* args[] = { &prm };
    lerr = hipLaunchCooperativeKernel((void*)k_mega, dim3(512), dim3(256), args, 0, stream);
  }
  if (lerr != hipSuccess) {
    (void)hipGetLastError();  // clear any sticky error
    hipLaunchKernelGGL(k_prep_k, dim3(8736), dim3(256), 0, stream, prm);
    hipLaunchKernelGGL(k_engine_k, dim3(512), dim3(256), 0, stream, prm);
    hipLaunchKernelGGL(k_gates_k, dim3(1024), dim3(256), 0, stream, prm);
    hipLaunchKernelGGL(k_cand_k, dim3(1024), dim3(256), 0, stream, prm);
    hipLaunchKernelGGL(k_fs_k, dim3(129), dim3(256), 0, stream, prm);
    hipLaunchKernelGGL(k_sc_k, dim3(8256), dim3(256), 0, stream, prm);
    hipLaunchKernelGGL(k_pp_k, dim3(16), dim3(256), 0, stream, prm);
    hipLaunchKernelGGL(k_pr_k, dim3(2), dim3(256), 0, stream, prm);
  }
}